// Round 7
// baseline (115.472 us; speedup 1.0000x reference)
//
#include <hip/hip_runtime.h>
#include <cstdint>
#include <cstddef>

typedef _Float16 f16;
typedef f16 f16x8 __attribute__((ext_vector_type(8)));
typedef f16 f16x4 __attribute__((ext_vector_type(4)));
typedef float floatx4 __attribute__((ext_vector_type(4)));

#define GAS __attribute__((address_space(1)))
#define LAS __attribute__((address_space(3)))

static constexpr int LSEQ = 2048;
static constexpr int NH   = 8;
static constexpr int DH   = 64;
static constexpr int DM   = 512;
static constexpr int WIN  = 64;
static constexpr int MR   = 4 * LSEQ;  // 8192 rows (B*L)

// ------------------------------------------- prep: cast x->f16  +  transpose W->f16
__global__ __launch_bounds__(256) void prep_kernel(
    const float* __restrict__ x, f16* __restrict__ xb,
    const float* __restrict__ Wq, const float* __restrict__ Wk,
    const float* __restrict__ Wv, const float* __restrict__ Wo,
    f16* __restrict__ wt) {
    __shared__ float tile[32][33];
    int bid = blockIdx.x;
    if (bid < 4096) {
        int i = bid * 256 + threadIdx.x;      // 4 elements/thread
        float4 v = ((const float4*)x)[i];
        f16x4 o = { (f16)v.x, (f16)v.y, (f16)v.z, (f16)v.w };
        ((f16x4*)xb)[i] = o;
    } else {
        int id = bid - 4096;
        int z  = id >> 8, t = id & 255;
        const float* W = z == 0 ? Wq : z == 1 ? Wk : z == 2 ? Wv : Wo;
        f16* out = wt + (size_t)z * DM * DM;
        int c0 = (t & 15) * 32, r0 = (t >> 4) * 32;
        int tx = threadIdx.x & 31, ty = threadIdx.x >> 5;
        #pragma unroll
        for (int i = 0; i < 32; i += 8)
            tile[ty + i][tx] = W[(size_t)(r0 + ty + i) * DM + c0 + tx];
        __syncthreads();
        #pragma unroll
        for (int i = 0; i < 32; i += 8)
            out[(size_t)(c0 + ty + i) * DM + r0 + tx] = (f16)tile[tx][ty + i];
    }
}

// ----------------------------------------------- GEMM: A-local / B-from-L2 structure
// Block = BM rows x ALL 512 cols, 8 waves; wave w owns 64 rows? no: wave w owns
// cols [w*64, w*64+64) x all BM rows. A-tile (BM x 512, 64/32 KB) staged to LDS
// ONCE (single drain); B read directly from global per wave -- the whole Bt panel
// (0.5 MB/z) is L2-resident on each XCD, so B re-reads never touch the fabric.
// A XOR swizzle: granule g' = g ^ (row&7), both sides (rule #21); read pattern
// identical to R1-R3's proven 0-conflict layout.
// Decode (chunked XCD swizzle): lin=(hw&7)*chunk+hw/8; QKV: m=lin&127, z=lin>>7.
template <bool QKV>
__global__ __launch_bounds__(512, 4) void gemm_kernel(
    const f16* __restrict__ A, const f16* __restrict__ Bt_base,
    const float* __restrict__ b0, const float* __restrict__ b1,
    const float* __restrict__ b2,
    f16* __restrict__ out_q, f16* __restrict__ out_k, f16* __restrict__ out_vt,
    float* __restrict__ out_f) {
    constexpr int BM = QKV ? 64 : 32;      // rows per block
    constexpr int MF = BM / 16;            // m-fragments
    constexpr int GR = BM * 64;            // 16B granules in A-tile
    const int chunk = gridDim.x >> 3;
    const int hw  = blockIdx.x;
    const int lin = (hw & 7) * chunk + (hw >> 3);
    const int m0  = (QKV ? (lin & 127) : lin) * BM;
    const int z   = QKV ? (lin >> 7) : 0;

    const f16* __restrict__ Bt = Bt_base + (size_t)z * (DM * DM);
    const float* __restrict__ bias = QKV ? (z == 0 ? b0 : z == 1 ? b1 : b2) : b0;

    __shared__ f16 As[BM * DM];            // [row][64 granules], granule-XOR-swizzled

    const int tid  = threadIdx.x;
    const int wid  = tid >> 6;             // 0..7 -> col group
    const int lane = tid & 63;
    const int l15  = lane & 15;
    const int l4   = lane >> 4;

    // ---- stage A-tile once: GR granules, XOR-swizzled source, linear LDS dest
    #pragma unroll
    for (int i = 0; i < GR / 512; ++i) {
        int gg  = i * 512 + tid;
        int row = gg >> 6, gp = gg & 63;
        int sg  = gp ^ (row & 7);
        const f16* g = A + (size_t)(m0 + row) * DM + sg * 8;
        f16* l = &As[(i * 512 + wid * 64) * 8];   // +lane*16B by HW
        __builtin_amdgcn_global_load_lds((const GAS void*)g, (LAS void*)l, 16, 0, 0);
    }
    __syncthreads();   // the only block-wide sync

    floatx4 acc[MF][4] = {};

    #pragma unroll 4
    for (int ks = 0; ks < 16; ++ks) {
        f16x8 af[MF], bfr[4];
        #pragma unroll
        for (int m = 0; m < MF; ++m) {
            int row = m * 16 + l15;
            int gp  = (ks * 4 + l4) ^ (row & 7);
            af[m] = *(const f16x8*)(&As[row * DM + gp * 8]);
        }
        #pragma unroll
        for (int n = 0; n < 4; ++n) {
            int col = wid * 64 + n * 16 + l15;
            bfr[n] = *(const f16x8*)(Bt + (size_t)col * DM + (ks * 4 + l4) * 8);
        }
        #pragma unroll
        for (int m = 0; m < MF; ++m)
            #pragma unroll
            for (int n = 0; n < 4; ++n)
                acc[m][n] = __builtin_amdgcn_mfma_f32_16x16x32_f16(af[m], bfr[n], acc[m][n], 0, 0, 0);
    }

    // epilogue; D layout: col = lane&15, row = (lane>>4)*4 + r  (m89-verified)
    #pragma unroll
    for (int n = 0; n < 4; ++n) {
        int gcol = wid * 64 + n * 16 + l15;
        float bias_v = bias[gcol];
        #pragma unroll
        for (int m = 0; m < MF; ++m) {
            int grow0 = m0 + m * 16 + l4 * 4;
            #pragma unroll
            for (int r = 0; r < 4; ++r) {
                int grow = grow0 + r;
                float v = acc[m][n][r] + bias_v;
                if constexpr (QKV) {
                    int b = grow >> 11, lp = grow & (LSEQ - 1);
                    int h = gcol >> 6,  d  = gcol & (DH - 1);
                    int bh = b * NH + h;
                    if (z == 0)       // Q, pre-scaled by 1/sqrt(Dh) (exact pow2)
                        out_q[((size_t)bh * LSEQ + lp) * DH + d] = (f16)(v * 0.125f);
                    else if (z == 1)  // K: [bh][l][d]
                        out_k[((size_t)bh * LSEQ + lp) * DH + d] = (f16)v;
                    else              // V transposed: [bh][d][l]
                        out_vt[((size_t)bh * DH + d) * LSEQ + lp] = (f16)v;
                } else {
                    out_f[(size_t)grow * DM + gcol] = v;
                }
            }
        }
    }
}

// ---------------------------------------------------------------- windowed attention
// 1-D grid 1024 + chunked-XCD swizzle (4 heads' K/V per XCD -> L2-resident).
// block: (64 queries of one bh), 4 waves x 16 queries; key window = 192 wide
__global__ __launch_bounds__(256) void attn_kernel(const f16* __restrict__ Qb,
                                                   const f16* __restrict__ Kb,
                                                   const f16* __restrict__ Vt,
                                                   f16* __restrict__ Ob) {
    const int hw  = blockIdx.x;
    const int lin = (hw & 7) * 128 + (hw >> 3);
    const int bh    = lin >> 5;
    const int q0blk = (lin & 31) * 64;
    const int wid    = threadIdx.x >> 6;
    const int lane   = threadIdx.x & 63;
    const int l15    = lane & 15, l4 = lane >> 4;
    const int qbase  = q0blk + wid * 16;
    const int kstart = q0blk - WIN;

    const f16* __restrict__ Q = Qb + (size_t)bh * LSEQ * DH;
    const f16* __restrict__ K = Kb + (size_t)bh * LSEQ * DH;
    const f16* __restrict__ V = Vt + (size_t)bh * DH * LSEQ;

    __shared__ f16 Pl[4][16][232];   // 464B row stride: 16B-aligned, bank-spread

    // Q fragments (A operand): row = l15, k = ks*32 + l4*8 + i
    f16x8 qf[2];
    #pragma unroll
    for (int ks = 0; ks < 2; ++ks)
        qf[ks] = *(const f16x8*)(Q + (size_t)(qbase + l15) * DH + ks * 32 + l4 * 8);

    // S = Q K^T : 12 n-tiles of 16 keys
    floatx4 sc[12] = {};
    #pragma unroll
    for (int nt = 0; nt < 12; ++nt) {
        int key = kstart + nt * 16 + l15;
        int kcl = key < 0 ? 0 : (key > LSEQ - 1 ? LSEQ - 1 : key);
        #pragma unroll
        for (int ks = 0; ks < 2; ++ks) {
            f16x8 kf = *(const f16x8*)(K + (size_t)kcl * DH + ks * 32 + l4 * 8);
            sc[nt] = __builtin_amdgcn_mfma_f32_16x16x32_f16(qf[ks], kf, sc[nt], 0, 0, 0);
        }
    }

    // mask + softmax. Row q = qbase + l4*4 + r lives in the 16 lanes sharing l4.
    float mx[4] = {-1e30f, -1e30f, -1e30f, -1e30f};
    #pragma unroll
    for (int nt = 0; nt < 12; ++nt) {
        int key = kstart + nt * 16 + l15;
        #pragma unroll
        for (int r = 0; r < 4; ++r) {
            int q = qbase + l4 * 4 + r;
            int dist = key - q; dist = dist < 0 ? -dist : dist;
            bool valid = (key >= 0) && (key < LSEQ) && (dist <= WIN);
            float s = valid ? sc[nt][r] : -1e30f;
            sc[nt][r] = s;
            mx[r] = fmaxf(mx[r], s);
        }
    }
    #pragma unroll
    for (int r = 0; r < 4; ++r)
        #pragma unroll
        for (int m = 1; m < 16; m <<= 1)
            mx[r] = fmaxf(mx[r], __shfl_xor(mx[r], m, 64));
    float sm[4] = {0.f, 0.f, 0.f, 0.f};
    #pragma unroll
    for (int nt = 0; nt < 12; ++nt)
        #pragma unroll
        for (int r = 0; r < 4; ++r) {
            float p = __expf(sc[nt][r] - mx[r]);
            sc[nt][r] = p;
            sm[r] += p;
        }
    #pragma unroll
    for (int r = 0; r < 4; ++r) {
        #pragma unroll
        for (int m = 1; m < 16; m <<= 1)
            sm[r] += __shfl_xor(sm[r], m, 64);
        sm[r] = 1.f / sm[r];
    }

    // P -> LDS in A-fragment-friendly layout
    #pragma unroll
    for (int nt = 0; nt < 12; ++nt)
        #pragma unroll
        for (int r = 0; r < 4; ++r)
            Pl[wid][l4 * 4 + r][nt * 16 + l15] = (f16)(sc[nt][r] * sm[r]);
    __syncthreads();

    // O = P V : A-frag from LDS (contiguous), B-frag from Vt (contiguous keys)
    floatx4 oc[4] = {};
    #pragma unroll
    for (int ks = 0; ks < 6; ++ks) {
        f16x8 pf = *(const f16x8*)(&Pl[wid][l15][ks * 32 + l4 * 8]);
        int kb0 = kstart + ks * 32 + l4 * 8;
        int kbc = (kb0 < 0 || kb0 > LSEQ - 8) ? 0 : kb0;  // whole chunk valid or P==0
        #pragma unroll
        for (int dt = 0; dt < 4; ++dt) {
            f16x8 vf = *(const f16x8*)(V + (size_t)(dt * 16 + l15) * LSEQ + kbc);
            oc[dt] = __builtin_amdgcn_mfma_f32_16x16x32_f16(pf, vf, oc[dt], 0, 0, 0);
        }
    }

    // write O in [B][L][H*64] f16 (A operand of final GEMM)
    int b = bh >> 3, h = bh & 7;
    #pragma unroll
    for (int dt = 0; dt < 4; ++dt) {
        int d = dt * 16 + l15;
        #pragma unroll
        for (int r = 0; r < 4; ++r) {
            int q = qbase + l4 * 4 + r;
            Ob[((size_t)b * LSEQ + q) * DM + h * DH + d] = (f16)oc[dt][r];
        }
    }
}

// ---------------------------------------------------------------- launch
extern "C" void kernel_launch(void* const* d_in, const int* in_sizes, int n_in,
                              void* d_out, int out_size, void* d_ws, size_t ws_size,
                              hipStream_t stream) {
    const float* x  = (const float*)d_in[0];
    const float* Wq = (const float*)d_in[1];
    const float* bq = (const float*)d_in[2];
    const float* Wk = (const float*)d_in[3];
    const float* bk = (const float*)d_in[4];
    const float* Wv = (const float*)d_in[5];
    const float* bv = (const float*)d_in[6];
    const float* Wo = (const float*)d_in[7];
    const float* bo = (const float*)d_in[8];
    float* out = (float*)d_out;

    char* ws = (char*)d_ws;
    f16* xb = (f16*)(ws);                       // 8 MB  [8192][512]
    f16* wt = (f16*)(ws + (8ull << 20));        // 2 MB  WqT,WkT,WvT,WoT
    f16* qb = (f16*)(ws + (10ull << 20));       // 8 MB  [32][2048][64], pre-scaled
    f16* kb = (f16*)(ws + (18ull << 20));       // 8 MB  [32][2048][64]
    f16* vt = (f16*)(ws + (26ull << 20));       // 8 MB  [32][64][2048]
    f16* ob = (f16*)(ws + (34ull << 20));       // 8 MB  [8192][512]

    prep_kernel<<<dim3(5120), 256, 0, stream>>>(x, xb, Wq, Wk, Wv, Wo, wt);
    gemm_kernel<true><<<dim3(384), 512, 0, stream>>>(
        xb, wt, bq, bk, bv, qb, kb, vt, nullptr);
    attn_kernel<<<dim3(1024), 256, 0, stream>>>(qb, kb, vt, ob);
    gemm_kernel<false><<<dim3(256), 512, 0, stream>>>(
        ob, wt + 3ull * DM * DM, bo, bo, bo, nullptr, nullptr, nullptr, out);
}

// Round 8
// 110.627 us; speedup vs baseline: 1.0438x; 1.0438x over previous
//
#include <hip/hip_runtime.h>
#include <cstdint>
#include <cstddef>

typedef _Float16 f16;
typedef f16 f16x8 __attribute__((ext_vector_type(8)));
typedef f16 f16x4 __attribute__((ext_vector_type(4)));
typedef float floatx4 __attribute__((ext_vector_type(4)));

static constexpr int LSEQ = 2048;
static constexpr int NH   = 8;
static constexpr int DH   = 64;
static constexpr int DM   = 512;
static constexpr int WIN  = 64;
static constexpr int MR   = 4 * LSEQ;  // 8192 rows (B*L)

// ------------------------------------------- prep: cast x->f16  +  pack W->fragment order
// blocks 0..4095: cast 1024 floats each.
// blocks 4096..4223: pack one (z, 16-col tile) of W into Bp[z][col16][ks][lane][8]:
//   col = col16*16 + c15, k = ks*32 + l4*8 + w  ->  a wave's B-fragment load is
//   one contiguous 1KB read (lane*16B), eliminating the scattered B gather.
__global__ __launch_bounds__(256) void prep_kernel(
    const float* __restrict__ x, f16* __restrict__ xb,
    const float* __restrict__ Wq, const float* __restrict__ Wk,
    const float* __restrict__ Wv, const float* __restrict__ Wo,
    f16* __restrict__ wt) {
    int bid = blockIdx.x;
    if (bid < 4096) {
        int i = bid * 256 + threadIdx.x;      // 4 elements/thread
        float4 v = ((const float4*)x)[i];
        f16x4 o = { (f16)v.x, (f16)v.y, (f16)v.z, (f16)v.w };
        ((f16x4*)xb)[i] = o;
    } else {
        int id = bid - 4096;                  // 0..127
        int z  = id >> 5, ct16 = id & 31;
        const float* W = z == 0 ? Wq : z == 1 ? Wk : z == 2 ? Wv : Wo;
        f16* dst = wt + (size_t)z * DM * DM;
        #pragma unroll
        for (int i = 0; i < 32; ++i) {
            int idx = i * 256 + threadIdx.x;  // 0..8191 over (c15, k)
            int c15 = idx & 15, k = idx >> 4;
            int ks = k >> 5, l4k = (k >> 3) & 3, w = k & 7;
            float v = W[(size_t)k * DM + ct16 * 16 + c15];
            dst[(size_t)(ct16 * 16 + ks) * 512 + (l4k * 16 + c15) * 8 + w] = (f16)v;
        }
    }
}

// ------------------------------------------- GEMM: pure register / direct-load (attn-style)
// NO LDS, NO barriers, NO global_load_lds. Each wave independently owns an
// MF*16 x 64 output tile. A-frags: 16-line gather (the measured-fast attn-K
// pattern; 4 waves/block share rows -> L1 reuse). B-frags: contiguous 1KB loads
// from the fragment-packed Bp (L2-resident, <=2MB/XCD).
// wave = (chunked-XCD lin)*4 + wid; QKV: z=wave>>10, rt=(wave&1023)>>3, ct=wave&7.
template <bool QKV>
__global__ __launch_bounds__(256, 4) void gemm_kernel(
    const f16* __restrict__ A, const f16* __restrict__ Bp_base,
    const float* __restrict__ b0, const float* __restrict__ b1,
    const float* __restrict__ b2,
    f16* __restrict__ out_q, f16* __restrict__ out_k, f16* __restrict__ out_vt,
    float* __restrict__ out_f) {
    constexpr int MF = QKV ? 4 : 2;        // m-fragments per wave (64 / 32 rows)
    const int chunk = gridDim.x >> 3;
    const int hw  = blockIdx.x;
    const int lin = (hw & 7) * chunk + (hw >> 3);
    const int wid  = threadIdx.x >> 6;
    const int lane = threadIdx.x & 63;
    const int wave = lin * 4 + wid;
    int z, rt, ct;
    if constexpr (QKV) { z = wave >> 10; int rem = wave & 1023; rt = rem >> 3; ct = rem & 7; }
    else               { z = 0; rt = wave >> 3; ct = wave & 7; }
    const int rbase = rt * (MF * 16);
    const int l15 = lane & 15, l4 = lane >> 4;

    const f16* __restrict__ pk = Bp_base + (size_t)z * DM * DM + (size_t)(ct * 4) * 16 * 512;
    const float* __restrict__ bias = QKV ? (z == 0 ? b0 : z == 1 ? b1 : b2) : b0;

    const f16* arow[MF];
    #pragma unroll
    for (int m = 0; m < MF; ++m)
        arow[m] = A + (size_t)(rbase + m * 16 + l15) * DM + l4 * 8;

    floatx4 acc[MF][4] = {};

    #pragma unroll 2
    for (int ks = 0; ks < 16; ++ks) {
        f16x8 af[MF], bf[4];
        #pragma unroll
        for (int m = 0; m < MF; ++m)
            af[m] = *(const f16x8*)(arow[m] + ks * 32);
        #pragma unroll
        for (int n = 0; n < 4; ++n)
            bf[n] = *(const f16x8*)(pk + (size_t)(n * 16 + ks) * 512 + lane * 8);
        #pragma unroll
        for (int m = 0; m < MF; ++m)
            #pragma unroll
            for (int n = 0; n < 4; ++n)
                acc[m][n] = __builtin_amdgcn_mfma_f32_16x16x32_f16(af[m], bf[n], acc[m][n], 0, 0, 0);
    }

    // epilogue; D layout: col = lane&15, row = (lane>>4)*4 + r  (m89-verified)
    #pragma unroll
    for (int n = 0; n < 4; ++n) {
        int gcol = ct * 64 + n * 16 + l15;
        float bias_v = bias[gcol];
        #pragma unroll
        for (int m = 0; m < MF; ++m) {
            int grow0 = rbase + m * 16 + l4 * 4;
            #pragma unroll
            for (int r = 0; r < 4; ++r) {
                int grow = grow0 + r;
                float v = acc[m][n][r] + bias_v;
                if constexpr (QKV) {
                    int b = grow >> 11, lp = grow & (LSEQ - 1);
                    int h = gcol >> 6,  d  = gcol & (DH - 1);
                    int bh = b * NH + h;
                    if (z == 0)       // Q, pre-scaled by 1/sqrt(Dh) (exact pow2)
                        out_q[((size_t)bh * LSEQ + lp) * DH + d] = (f16)(v * 0.125f);
                    else if (z == 1)  // K: [bh][l][d]
                        out_k[((size_t)bh * LSEQ + lp) * DH + d] = (f16)v;
                    else              // V transposed: [bh][d][l]
                        out_vt[((size_t)bh * DH + d) * LSEQ + lp] = (f16)v;
                } else {
                    out_f[(size_t)grow * DM + gcol] = v;
                }
            }
        }
    }
}

// ---------------------------------------------------------------- windowed attention
// 1-D grid 1024 + chunked-XCD swizzle (4 heads' K/V per XCD -> L2-resident).
// block: (64 queries of one bh), 4 waves x 16 queries; key window = 192 wide
__global__ __launch_bounds__(256) void attn_kernel(const f16* __restrict__ Qb,
                                                   const f16* __restrict__ Kb,
                                                   const f16* __restrict__ Vt,
                                                   f16* __restrict__ Ob) {
    const int hw  = blockIdx.x;
    const int lin = (hw & 7) * 128 + (hw >> 3);
    const int bh    = lin >> 5;
    const int q0blk = (lin & 31) * 64;
    const int wid    = threadIdx.x >> 6;
    const int lane   = threadIdx.x & 63;
    const int l15    = lane & 15, l4 = lane >> 4;
    const int qbase  = q0blk + wid * 16;
    const int kstart = q0blk - WIN;

    const f16* __restrict__ Q = Qb + (size_t)bh * LSEQ * DH;
    const f16* __restrict__ K = Kb + (size_t)bh * LSEQ * DH;
    const f16* __restrict__ V = Vt + (size_t)bh * DH * LSEQ;

    __shared__ f16 Pl[4][16][232];   // 464B row stride: 16B-aligned, bank-spread

    // Q fragments (A operand): row = l15, k = ks*32 + l4*8 + i
    f16x8 qf[2];
    #pragma unroll
    for (int ks = 0; ks < 2; ++ks)
        qf[ks] = *(const f16x8*)(Q + (size_t)(qbase + l15) * DH + ks * 32 + l4 * 8);

    // S = Q K^T : 12 n-tiles of 16 keys
    floatx4 sc[12] = {};
    #pragma unroll
    for (int nt = 0; nt < 12; ++nt) {
        int key = kstart + nt * 16 + l15;
        int kcl = key < 0 ? 0 : (key > LSEQ - 1 ? LSEQ - 1 : key);
        #pragma unroll
        for (int ks = 0; ks < 2; ++ks) {
            f16x8 kf = *(const f16x8*)(K + (size_t)kcl * DH + ks * 32 + l4 * 8);
            sc[nt] = __builtin_amdgcn_mfma_f32_16x16x32_f16(qf[ks], kf, sc[nt], 0, 0, 0);
        }
    }

    // mask + softmax. Row q = qbase + l4*4 + r lives in the 16 lanes sharing l4.
    float mx[4] = {-1e30f, -1e30f, -1e30f, -1e30f};
    #pragma unroll
    for (int nt = 0; nt < 12; ++nt) {
        int key = kstart + nt * 16 + l15;
        #pragma unroll
        for (int r = 0; r < 4; ++r) {
            int q = qbase + l4 * 4 + r;
            int dist = key - q; dist = dist < 0 ? -dist : dist;
            bool valid = (key >= 0) && (key < LSEQ) && (dist <= WIN);
            float s = valid ? sc[nt][r] : -1e30f;
            sc[nt][r] = s;
            mx[r] = fmaxf(mx[r], s);
        }
    }
    #pragma unroll
    for (int r = 0; r < 4; ++r)
        #pragma unroll
        for (int m = 1; m < 16; m <<= 1)
            mx[r] = fmaxf(mx[r], __shfl_xor(mx[r], m, 64));
    float sm[4] = {0.f, 0.f, 0.f, 0.f};
    #pragma unroll
    for (int nt = 0; nt < 12; ++nt)
        #pragma unroll
        for (int r = 0; r < 4; ++r) {
            float p = __expf(sc[nt][r] - mx[r]);
            sc[nt][r] = p;
            sm[r] += p;
        }
    #pragma unroll
    for (int r = 0; r < 4; ++r) {
        #pragma unroll
        for (int m = 1; m < 16; m <<= 1)
            sm[r] += __shfl_xor(sm[r], m, 64);
        sm[r] = 1.f / sm[r];
    }

    // P -> LDS in A-fragment-friendly layout
    #pragma unroll
    for (int nt = 0; nt < 12; ++nt)
        #pragma unroll
        for (int r = 0; r < 4; ++r)
            Pl[wid][l4 * 4 + r][nt * 16 + l15] = (f16)(sc[nt][r] * sm[r]);
    __syncthreads();

    // O = P V : A-frag from LDS (contiguous), B-frag from Vt (contiguous keys)
    floatx4 oc[4] = {};
    #pragma unroll
    for (int ks = 0; ks < 6; ++ks) {
        f16x8 pf = *(const f16x8*)(&Pl[wid][l15][ks * 32 + l4 * 8]);
        int kb0 = kstart + ks * 32 + l4 * 8;
        int kbc = (kb0 < 0 || kb0 > LSEQ - 8) ? 0 : kb0;  // whole chunk valid or P==0
        #pragma unroll
        for (int dt = 0; dt < 4; ++dt) {
            f16x8 vf = *(const f16x8*)(V + (size_t)(dt * 16 + l15) * LSEQ + kbc);
            oc[dt] = __builtin_amdgcn_mfma_f32_16x16x32_f16(pf, vf, oc[dt], 0, 0, 0);
        }
    }

    // write O in [B][L][H*64] f16 (A operand of final GEMM)
    int b = bh >> 3, h = bh & 7;
    #pragma unroll
    for (int dt = 0; dt < 4; ++dt) {
        int d = dt * 16 + l15;
        #pragma unroll
        for (int r = 0; r < 4; ++r) {
            int q = qbase + l4 * 4 + r;
            Ob[((size_t)b * LSEQ + q) * DM + h * DH + d] = (f16)oc[dt][r];
        }
    }
}

// ---------------------------------------------------------------- launch
extern "C" void kernel_launch(void* const* d_in, const int* in_sizes, int n_in,
                              void* d_out, int out_size, void* d_ws, size_t ws_size,
                              hipStream_t stream) {
    const float* x  = (const float*)d_in[0];
    const float* Wq = (const float*)d_in[1];
    const float* bq = (const float*)d_in[2];
    const float* Wk = (const float*)d_in[3];
    const float* bk = (const float*)d_in[4];
    const float* Wv = (const float*)d_in[5];
    const float* bv = (const float*)d_in[6];
    const float* Wo = (const float*)d_in[7];
    const float* bo = (const float*)d_in[8];
    float* out = (float*)d_out;

    char* ws = (char*)d_ws;
    f16* xb = (f16*)(ws);                       // 8 MB  [8192][512]
    f16* wt = (f16*)(ws + (8ull << 20));        // 2 MB  fragment-packed Wq,Wk,Wv,Wo
    f16* qb = (f16*)(ws + (10ull << 20));       // 8 MB  [32][2048][64], pre-scaled
    f16* kb = (f16*)(ws + (18ull << 20));       // 8 MB  [32][2048][64]
    f16* vt = (f16*)(ws + (26ull << 20));       // 8 MB  [32][64][2048]
    f16* ob = (f16*)(ws + (34ull << 20));       // 8 MB  [8192][512]

    prep_kernel<<<dim3(4224), 256, 0, stream>>>(x, xb, Wq, Wk, Wv, Wo, wt);
    gemm_kernel<true><<<dim3(768), 256, 0, stream>>>(
        xb, wt, bq, bk, bv, qb, kb, vt, nullptr);
    attn_kernel<<<dim3(1024), 256, 0, stream>>>(qb, kb, vt, ob);
    gemm_kernel<false><<<dim3(512), 256, 0, stream>>>(
        ob, wt + 3ull * DM * DM, bo, bo, bo, nullptr, nullptr, nullptr, out);
}

// Round 9
// 93.902 us; speedup vs baseline: 1.2297x; 1.1781x over previous
//
#include <hip/hip_runtime.h>
#include <cstdint>
#include <cstddef>

typedef _Float16 f16;
typedef f16 f16x8 __attribute__((ext_vector_type(8)));
typedef f16 f16x4 __attribute__((ext_vector_type(4)));
typedef float floatx4 __attribute__((ext_vector_type(4)));

#define GAS __attribute__((address_space(1)))
#define LAS __attribute__((address_space(3)))

static constexpr int LSEQ = 2048;
static constexpr int NH   = 8;
static constexpr int DH   = 64;
static constexpr int DM   = 512;
static constexpr int WIN  = 64;
static constexpr int MR   = 4 * LSEQ;  // 8192 rows (B*L)

// ------------------------------------------- prep: cast x->f16  +  transpose W->Bt f16
__global__ __launch_bounds__(256) void prep_kernel(
    const float* __restrict__ x, f16* __restrict__ xb,
    const float* __restrict__ Wq, const float* __restrict__ Wk,
    const float* __restrict__ Wv, const float* __restrict__ Wo,
    f16* __restrict__ wt) {
    __shared__ float tile[32][33];
    int bid = blockIdx.x;
    if (bid < 4096) {
        int i = bid * 256 + threadIdx.x;      // 4 elements/thread
        float4 v = ((const float4*)x)[i];
        f16x4 o = { (f16)v.x, (f16)v.y, (f16)v.z, (f16)v.w };
        ((f16x4*)xb)[i] = o;
    } else {
        int id = bid - 4096;
        int z  = id >> 8, t = id & 255;
        const float* W = z == 0 ? Wq : z == 1 ? Wk : z == 2 ? Wv : Wo;
        f16* out = wt + (size_t)z * DM * DM;
        int c0 = (t & 15) * 32, r0 = (t >> 4) * 32;
        int tx = threadIdx.x & 31, ty = threadIdx.x >> 5;
        #pragma unroll
        for (int i = 0; i < 32; i += 8)
            tile[ty + i][tx] = W[(size_t)(r0 + ty + i) * DM + c0 + tx];
        __syncthreads();
        #pragma unroll
        for (int i = 0; i < 32; i += 8)
            out[(size_t)(c0 + ty + i) * DM + r0 + tx] = (f16)tile[tx][ty + i];
    }
}

// --------------------------------------- GEMM: 256xBN tile, 8 waves, BK=64, dbuf
// Fat-tile amortization of the per-K-step overhead (m102 K-scaling diagnosis):
// 64 MFMA per wave per K-step (BN=256) vs the 16 of all prior rounds. Schedule is
// R3's proven counted-vmcnt double-buffer (validated numerically R3-R5).
// Wave grid: WAVES_M x WAVES_N over the 256xBN tile; wave owns MF*16 x 64 out.
// XOR swizzle pair on A/B rows (granule kc ^= row&7), rule #21 compliant.
template <int ZN, int BN>   // ZN: weight matrices (3=QKV, 1=out-proj); BN: 256 or 128
__global__ __launch_bounds__(512, 1) void gemm_kernel(
    const f16* __restrict__ A, const f16* __restrict__ Bt_base,
    const float* __restrict__ b0, const float* __restrict__ b1,
    const float* __restrict__ b2,
    f16* __restrict__ out_q, f16* __restrict__ out_k, f16* __restrict__ out_vt,
    float* __restrict__ out_f) {
    constexpr int NT      = DM / BN;        // n-tiles per z (2 or 4)
    constexpr int WAVES_N = BN / 64;        // 4 or 2
    constexpr int WAVES_M = 8 / WAVES_N;    // 2 or 4
    constexpr int WM      = 256 / WAVES_M;  // rows per wave: 128 or 64
    constexpr int MF      = WM / 16;        // m-frags: 8 or 4
    constexpr int AI      = 4;              // A stage insts/thread (2048 granules/512)
    constexpr int BI      = BN * 8 / 512;   // B stage insts/thread (4 or 2)
    constexpr int STEADY  = AI + BI;        // outstanding loads of newest buffer

    const int chunkX = gridDim.x >> 3;
    const int hw  = blockIdx.x;
    const int lin = (hw & 7) * chunkX + (hw >> 3);
    const int m_t = lin / (NT * ZN);
    const int rr  = lin % (NT * ZN);
    const int n_t = rr % NT;
    const int z   = rr / NT;
    const int m0  = m_t * 256;
    const int n0  = n_t * BN;

    const f16* __restrict__ Bt = Bt_base + (size_t)z * (DM * DM);
    const float* __restrict__ bias = (ZN == 3) ? (z == 0 ? b0 : z == 1 ? b1 : b2) : b0;

    __shared__ f16 As[2][256 * 64];   // 64 KB
    __shared__ f16 Bs[2][BN * 64];    // 64/32 KB

    const int tid  = threadIdx.x;
    const int wid  = tid >> 6;
    const int lane = tid & 63;
    const int l15  = lane & 15;
    const int l4   = lane >> 4;
    const int wrow = wid / WAVES_N;        // 0..WAVES_M-1
    const int wcol = wid % WAVES_N;        // 0..WAVES_N-1

    floatx4 acc[MF][4] = {};

    // stage tile k0 into buffer buf: XOR-swizzled SOURCE, linear LDS dest (rule #21)
    auto stage = [&](int buf, int k0) {
        #pragma unroll
        for (int i = 0; i < AI; ++i) {
            int c   = i * 512 + tid;
            int row = c >> 3, cw = c & 7;
            int cs  = cw ^ (row & 7);
            const f16* ga = A + (size_t)(m0 + row) * DM + k0 + cs * 8;
            f16* la = &As[buf][(i * 512 + wid * 64) * 8];
            __builtin_amdgcn_global_load_lds((const GAS void*)ga, (LAS void*)la, 16, 0, 0);
        }
        #pragma unroll
        for (int i = 0; i < BI; ++i) {
            int c   = i * 512 + tid;
            int row = c >> 3, cw = c & 7;
            int cs  = cw ^ (row & 7);
            const f16* gb = Bt + (size_t)(n0 + row) * DM + k0 + cs * 8;
            f16* lb = &Bs[buf][(i * 512 + wid * 64) * 8];
            __builtin_amdgcn_global_load_lds((const GAS void*)gb, (LAS void*)lb, 16, 0, 0);
        }
    };
    auto compute = [&](int buf) {
        #pragma unroll
        for (int ks = 0; ks < 2; ++ks) {
            f16x8 af[MF], bfr[4];
            #pragma unroll
            for (int m = 0; m < MF; ++m) {
                int row = wrow * WM + m * 16 + l15;
                int kc  = (ks * 4 + l4) ^ (row & 7);
                af[m] = *(const f16x8*)(&As[buf][row * 64 + kc * 8]);
            }
            #pragma unroll
            for (int n = 0; n < 4; ++n) {
                int row = wcol * 64 + n * 16 + l15;
                int kc  = (ks * 4 + l4) ^ (row & 7);
                bfr[n] = *(const f16x8*)(&Bs[buf][row * 64 + kc * 8]);
            }
            #pragma unroll
            for (int m = 0; m < MF; ++m)
                #pragma unroll
                for (int n = 0; n < 4; ++n)
                    acc[m][n] = __builtin_amdgcn_mfma_f32_16x16x32_f16(af[m], bfr[n], acc[m][n], 0, 0, 0);
        }
    };

    stage(0, 0);
    stage(1, 64);
    #pragma unroll
    for (int t = 0; t < 8; ++t) {
        // oldest buffer's loads are the first STEADY outstanding; keep newest in flight
        if (t < 7) {
            if constexpr (STEADY == 8) asm volatile("s_waitcnt vmcnt(8)" ::: "memory");
            else                       asm volatile("s_waitcnt vmcnt(6)" ::: "memory");
        } else {
            asm volatile("s_waitcnt vmcnt(0)" ::: "memory");
        }
        __builtin_amdgcn_sched_barrier(0);
        __builtin_amdgcn_s_barrier();      // all waves' buffer-t loads landed
        __builtin_amdgcn_sched_barrier(0);
        compute(t & 1);
        if (t < 6) {
            __builtin_amdgcn_s_barrier();  // all waves done reading buf t&1
            __builtin_amdgcn_sched_barrier(0);
            stage(t & 1, (t + 2) * 64);    // overwrite with tile t+2
        }
    }

    // epilogue; D layout: col = lane&15, row = (lane>>4)*4 + r  (m89-verified)
    #pragma unroll
    for (int n = 0; n < 4; ++n) {
        int gcol = n0 + wcol * 64 + n * 16 + l15;
        float bias_v = bias[gcol];
        #pragma unroll
        for (int m = 0; m < MF; ++m) {
            int grow0 = m0 + wrow * WM + m * 16 + l4 * 4;
            #pragma unroll
            for (int r = 0; r < 4; ++r) {
                int grow = grow0 + r;
                float v = acc[m][n][r] + bias_v;
                if constexpr (ZN == 3) {
                    int b = grow >> 11, lp = grow & (LSEQ - 1);
                    int h = gcol >> 6,  d  = gcol & (DH - 1);
                    int bh = b * NH + h;
                    if (z == 0)       // Q, pre-scaled by 1/sqrt(Dh) (exact pow2)
                        out_q[((size_t)bh * LSEQ + lp) * DH + d] = (f16)(v * 0.125f);
                    else if (z == 1)  // K: [bh][l][d]
                        out_k[((size_t)bh * LSEQ + lp) * DH + d] = (f16)v;
                    else              // V transposed: [bh][d][l]
                        out_vt[((size_t)bh * DH + d) * LSEQ + lp] = (f16)v;
                } else {
                    out_f[(size_t)grow * DM + gcol] = v;
                }
            }
        }
    }
}

// ---------------------------------------------------------------- windowed attention
// 1-D grid 1024 + chunked-XCD swizzle; block = 64 queries of one bh, 4 waves.
__global__ __launch_bounds__(256) void attn_kernel(const f16* __restrict__ Qb,
                                                   const f16* __restrict__ Kb,
                                                   const f16* __restrict__ Vt,
                                                   f16* __restrict__ Ob) {
    const int hw  = blockIdx.x;
    const int lin = (hw & 7) * 128 + (hw >> 3);
    const int bh    = lin >> 5;
    const int q0blk = (lin & 31) * 64;
    const int wid    = threadIdx.x >> 6;
    const int lane   = threadIdx.x & 63;
    const int l15    = lane & 15, l4 = lane >> 4;
    const int qbase  = q0blk + wid * 16;
    const int kstart = q0blk - WIN;

    const f16* __restrict__ Q = Qb + (size_t)bh * LSEQ * DH;
    const f16* __restrict__ K = Kb + (size_t)bh * LSEQ * DH;
    const f16* __restrict__ V = Vt + (size_t)bh * DH * LSEQ;

    __shared__ f16 Pl[4][16][232];   // 464B row stride: 16B-aligned, bank-spread

    f16x8 qf[2];
    #pragma unroll
    for (int ks = 0; ks < 2; ++ks)
        qf[ks] = *(const f16x8*)(Q + (size_t)(qbase + l15) * DH + ks * 32 + l4 * 8);

    floatx4 sc[12] = {};
    #pragma unroll
    for (int nt = 0; nt < 12; ++nt) {
        int key = kstart + nt * 16 + l15;
        int kcl = key < 0 ? 0 : (key > LSEQ - 1 ? LSEQ - 1 : key);
        #pragma unroll
        for (int ks = 0; ks < 2; ++ks) {
            f16x8 kf = *(const f16x8*)(K + (size_t)kcl * DH + ks * 32 + l4 * 8);
            sc[nt] = __builtin_amdgcn_mfma_f32_16x16x32_f16(qf[ks], kf, sc[nt], 0, 0, 0);
        }
    }

    float mx[4] = {-1e30f, -1e30f, -1e30f, -1e30f};
    #pragma unroll
    for (int nt = 0; nt < 12; ++nt) {
        int key = kstart + nt * 16 + l15;
        #pragma unroll
        for (int r = 0; r < 4; ++r) {
            int q = qbase + l4 * 4 + r;
            int dist = key - q; dist = dist < 0 ? -dist : dist;
            bool valid = (key >= 0) && (key < LSEQ) && (dist <= WIN);
            float s = valid ? sc[nt][r] : -1e30f;
            sc[nt][r] = s;
            mx[r] = fmaxf(mx[r], s);
        }
    }
    #pragma unroll
    for (int r = 0; r < 4; ++r)
        #pragma unroll
        for (int m = 1; m < 16; m <<= 1)
            mx[r] = fmaxf(mx[r], __shfl_xor(mx[r], m, 64));
    float sm[4] = {0.f, 0.f, 0.f, 0.f};
    #pragma unroll
    for (int nt = 0; nt < 12; ++nt)
        #pragma unroll
        for (int r = 0; r < 4; ++r) {
            float p = __expf(sc[nt][r] - mx[r]);
            sc[nt][r] = p;
            sm[r] += p;
        }
    #pragma unroll
    for (int r = 0; r < 4; ++r) {
        #pragma unroll
        for (int m = 1; m < 16; m <<= 1)
            sm[r] += __shfl_xor(sm[r], m, 64);
        sm[r] = 1.f / sm[r];
    }

    #pragma unroll
    for (int nt = 0; nt < 12; ++nt)
        #pragma unroll
        for (int r = 0; r < 4; ++r)
            Pl[wid][l4 * 4 + r][nt * 16 + l15] = (f16)(sc[nt][r] * sm[r]);
    __syncthreads();

    floatx4 oc[4] = {};
    #pragma unroll
    for (int ks = 0; ks < 6; ++ks) {
        f16x8 pf = *(const f16x8*)(&Pl[wid][l15][ks * 32 + l4 * 8]);
        int kb0 = kstart + ks * 32 + l4 * 8;
        int kbc = (kb0 < 0 || kb0 > LSEQ - 8) ? 0 : kb0;  // whole chunk valid or P==0
        #pragma unroll
        for (int dt = 0; dt < 4; ++dt) {
            f16x8 vf = *(const f16x8*)(V + (size_t)(dt * 16 + l15) * LSEQ + kbc);
            oc[dt] = __builtin_amdgcn_mfma_f32_16x16x32_f16(pf, vf, oc[dt], 0, 0, 0);
        }
    }

    int b = bh >> 3, h = bh & 7;
    #pragma unroll
    for (int dt = 0; dt < 4; ++dt) {
        int d = dt * 16 + l15;
        #pragma unroll
        for (int r = 0; r < 4; ++r) {
            int q = qbase + l4 * 4 + r;
            Ob[((size_t)b * LSEQ + q) * DM + h * DH + d] = (f16)oc[dt][r];
        }
    }
}

// ---------------------------------------------------------------- launch
extern "C" void kernel_launch(void* const* d_in, const int* in_sizes, int n_in,
                              void* d_out, int out_size, void* d_ws, size_t ws_size,
                              hipStream_t stream) {
    const float* x  = (const float*)d_in[0];
    const float* Wq = (const float*)d_in[1];
    const float* bq = (const float*)d_in[2];
    const float* Wk = (const float*)d_in[3];
    const float* bk = (const float*)d_in[4];
    const float* Wv = (const float*)d_in[5];
    const float* bv = (const float*)d_in[6];
    const float* Wo = (const float*)d_in[7];
    const float* bo = (const float*)d_in[8];
    float* out = (float*)d_out;

    char* ws = (char*)d_ws;
    f16* xb = (f16*)(ws);                       // 8 MB  [8192][512]
    f16* wt = (f16*)(ws + (8ull << 20));        // 2 MB  WqT,WkT,WvT,WoT
    f16* qb = (f16*)(ws + (10ull << 20));       // 8 MB  [32][2048][64], pre-scaled
    f16* kb = (f16*)(ws + (18ull << 20));       // 8 MB  [32][2048][64]
    f16* vt = (f16*)(ws + (26ull << 20));       // 8 MB  [32][64][2048]
    f16* ob = (f16*)(ws + (34ull << 20));       // 8 MB  [8192][512]

    prep_kernel<<<dim3(5120), 256, 0, stream>>>(x, xb, Wq, Wk, Wv, Wo, wt);
    // QKV: 32 m-tiles x 2 n-tiles x 3 z = 192 blocks of 256x256
    gemm_kernel<3, 256><<<dim3(192), 512, 0, stream>>>(
        xb, wt, bq, bk, bv, qb, kb, vt, nullptr);
    attn_kernel<<<dim3(1024), 256, 0, stream>>>(qb, kb, vt, ob);
    // out-proj: 32 m-tiles x 4 n-tiles = 128 blocks of 256x128
    gemm_kernel<1, 128><<<dim3(128), 512, 0, stream>>>(
        ob, wt + 3ull * DM * DM, bo, bo, bo, nullptr, nullptr, nullptr, out);
}